// Round 1
// baseline (144.002 us; speedup 1.0000x reference)
//
#include <hip/hip_runtime.h>
#include <stdint.h>

#define NB   8
#define CH   512
#define NPIX 1024
#define DH   64

typedef float  f32x4  __attribute__((ext_vector_type(4)));
typedef __bf16 bf16x8 __attribute__((ext_vector_type(8)));

static __device__ __forceinline__ unsigned short f2bf(float f) {
    unsigned int u = __builtin_bit_cast(unsigned int, f);
    u += 0x7FFFu + ((u >> 16) & 1u);   // RNE
    return (unsigned short)(u >> 16);
}

static __device__ __forceinline__ bf16x8 ld_bf8(const unsigned short* p) {
    return *reinterpret_cast<const bf16x8*>(p);
}

// ---------------- weights fp32 -> bf16, packed Wq|Wk|Wv|Wo ----------------
__global__ __launch_bounds__(256) void wconv_kernel(
        const float* __restrict__ Wq, const float* __restrict__ Wk,
        const float* __restrict__ Wv, const float* __restrict__ Wo,
        unsigned short* __restrict__ out) {
    int idx = blockIdx.x * 256 + threadIdx.x;          // 0 .. 4*512*512-1
    int which = idx >> 18;
    int off   = idx & 0x3FFFF;
    const float* src = which == 0 ? Wq : which == 1 ? Wk : which == 2 ? Wv : Wo;
    out[idx] = f2bf(src[off]);
}

// ------------- [b][c][n] fp32 -> [b][n][c] bf16 (x and context) -----------
__global__ __launch_bounds__(256) void tconv_kernel(
        const float* __restrict__ x, const float* __restrict__ ctx,
        unsigned short* __restrict__ XT, unsigned short* __restrict__ CT) {
    __shared__ float tile[32][33];
    const int z = blockIdx.z;                 // 0..15 : tensor(2) x batch(8)
    const float* src = (z < 8) ? x : ctx;
    unsigned short* dst = (z < 8) ? XT : CT;
    const int b  = z & 7;
    const int c0 = blockIdx.x * 32, n0 = blockIdx.y * 32;
    const int tx = threadIdx.x, ty = threadIdx.y;
    const float* s = src + (size_t)b * CH * NPIX;
#pragma unroll
    for (int i = 0; i < 4; i++) {
        int r = i * 8 + ty;
        tile[r][tx] = s[(size_t)(c0 + r) * NPIX + n0 + tx];
    }
    __syncthreads();
    unsigned short* d = dst + (size_t)b * NPIX * CH;
#pragma unroll
    for (int i = 0; i < 4; i++) {
        int r = i * 8 + ty;
        d[(size_t)(n0 + r) * CH + c0 + tx] = f2bf(tile[tx][r]);
    }
}

// ---------------- shared 128x128xK512 GEMM core (BK=32) -------------------
// Out[o][n] = sum_c W[o][c] * X[n][c]   (A = W rows, B^T = X rows)
static __device__ __forceinline__ void gemm128(
        const unsigned short* __restrict__ Wp,   // + o0*CH already
        const unsigned short* __restrict__ Xp,   // + (b,n0)*CH already
        f32x4 acc[4][4]) {
    __shared__ __align__(16) unsigned short lA[128][32];
    __shared__ __align__(16) unsigned short lB[128][32];
    const int tid  = threadIdx.x;
    const int lane = tid & 63;
    const int wm   = (tid >> 6) & 1, wn = tid >> 7;
    const int rr   = tid >> 2;            // 0..63
    const int cc   = (tid & 3) * 8;       // 0,8,16,24
#pragma unroll 1
    for (int kt = 0; kt < 16; kt++) {
        const int k0 = kt * 32;
        __syncthreads();
        *(uint4*)&lA[rr][cc]      = *(const uint4*)(Wp + (size_t)rr * CH + k0 + cc);
        *(uint4*)&lA[64 + rr][cc] = *(const uint4*)(Wp + (size_t)(64 + rr) * CH + k0 + cc);
        *(uint4*)&lB[rr][cc]      = *(const uint4*)(Xp + (size_t)rr * CH + k0 + cc);
        *(uint4*)&lB[64 + rr][cc] = *(const uint4*)(Xp + (size_t)(64 + rr) * CH + k0 + cc);
        __syncthreads();
        bf16x8 af[4], bfrag[4];
#pragma unroll
        for (int i = 0; i < 4; i++)
            af[i] = ld_bf8(&lA[wm * 64 + i * 16 + (lane & 15)][(lane >> 4) * 8]);
#pragma unroll
        for (int j = 0; j < 4; j++)
            bfrag[j] = ld_bf8(&lB[wn * 64 + j * 16 + (lane & 15)][(lane >> 4) * 8]);
#pragma unroll
        for (int i = 0; i < 4; i++)
#pragma unroll
            for (int j = 0; j < 4; j++)
                acc[i][j] = __builtin_amdgcn_mfma_f32_16x16x32_bf16(af[i], bfrag[j], acc[i][j], 0, 0, 0);
    }
}

// ---------------- fused Q/K/V projection --------------------------------
__global__ __launch_bounds__(256) void proj_qkv_kernel(
        const unsigned short* __restrict__ XT, const unsigned short* __restrict__ CT,
        const unsigned short* __restrict__ Wbf,
        const float* __restrict__ bq, const float* __restrict__ bk, const float* __restrict__ bv,
        unsigned short* __restrict__ Q, unsigned short* __restrict__ K, unsigned short* __restrict__ V) {
    const int z = blockIdx.z;
    const int b = z / 3, mode = z - 3 * b;       // 0=Q 1=K 2=V
    const int o0 = blockIdx.x * 128, n0 = blockIdx.y * 128;
    const unsigned short* W = Wbf + (size_t)mode * CH * CH;
    const unsigned short* X = (mode == 0 ? XT : CT) + (size_t)b * NPIX * CH;
    const float* bias = mode == 0 ? bq : mode == 1 ? bk : bv;

    f32x4 acc[4][4];
#pragma unroll
    for (int i = 0; i < 4; i++)
#pragma unroll
        for (int j = 0; j < 4; j++)
#pragma unroll
            for (int r = 0; r < 4; r++) acc[i][j][r] = 0.f;

    gemm128(W + (size_t)o0 * CH, X + (size_t)n0 * CH, acc);

    const int lane = threadIdx.x & 63;
    const int wm = (threadIdx.x >> 6) & 1, wn = threadIdx.x >> 7;
    const float qs = 0.125f * 1.44269504088896340736f;   // dim_head^-0.5 * log2(e)
#pragma unroll
    for (int i = 0; i < 4; i++) {
        const int ob = o0 + wm * 64 + i * 16 + (lane >> 4) * 4;
        const int h = ob >> 6, dd = ob & 63;
        float b4[4];
#pragma unroll
        for (int r = 0; r < 4; r++) b4[r] = bias[ob + r];
#pragma unroll
        for (int j = 0; j < 4; j++) {
            const int n = n0 + wn * 64 + j * 16 + (lane & 15);
            float v[4];
#pragma unroll
            for (int r = 0; r < 4; r++) v[r] = acc[i][j][r] + b4[r];
            if (mode == 0) {
#pragma unroll
                for (int r = 0; r < 4; r++) v[r] *= qs;
            }
            if (mode <= 1) {
                unsigned int lo = (unsigned)f2bf(v[0]) | ((unsigned)f2bf(v[1]) << 16);
                unsigned int hi = (unsigned)f2bf(v[2]) | ((unsigned)f2bf(v[3]) << 16);
                unsigned short* dst = (mode == 0 ? Q : K) +
                    (((size_t)(b * 8 + h) * NPIX) + n) * DH + dd;
                *(uint2*)dst = make_uint2(lo, hi);
            } else {
#pragma unroll
                for (int r = 0; r < 4; r++)
                    V[(((size_t)(b * 8 + h) * DH) + dd + r) * NPIX + n] = f2bf(v[r]);
            }
        }
    }
}

// ---------------- flash attention (base-2 softmax, scale pre-folded) ------
__global__ __launch_bounds__(256) void attn_kernel(
        const unsigned short* __restrict__ Qg, const unsigned short* __restrict__ Kg,
        const unsigned short* __restrict__ Vg, unsigned short* __restrict__ AT) {
    __shared__ __align__(16) unsigned short ldsK[64][72];   // +8 pad: uniform banks
    __shared__ __align__(16) unsigned short ldsV[64][72];
    __shared__ __align__(16) unsigned short ldsP[4][32][72];
    const int bh = blockIdx.y;                 // b*8+h
    const int q0 = blockIdx.x * 128;
    const int tid = threadIdx.x, wave = tid >> 6, lane = tid & 63;

    // Q fragments held in registers for the whole kernel
    const unsigned short* Qb = Qg + ((size_t)bh * NPIX + q0 + wave * 32) * DH;
    bf16x8 aq[2][2];
#pragma unroll
    for (int mi = 0; mi < 2; mi++)
#pragma unroll
        for (int ks = 0; ks < 2; ks++)
            aq[mi][ks] = ld_bf8(Qb + (size_t)(mi * 16 + (lane & 15)) * DH + ks * 32 + (lane >> 4) * 8);

    f32x4 acc[2][4];
    float m_run[2][4], l_run[2][4];
#pragma unroll
    for (int mi = 0; mi < 2; mi++)
#pragma unroll
        for (int r = 0; r < 4; r++) {
            m_run[mi][r] = -3.0e38f; l_run[mi][r] = 0.f;
#pragma unroll
            for (int di = 0; di < 4; di++) acc[mi][di][r] = 0.f;
        }

    const int srow = tid >> 3, scol = (tid & 7) * 8;
#pragma unroll 1
    for (int jt = 0; jt < 16; jt++) {
        const int j0 = jt * 64;
        __syncthreads();
#pragma unroll
        for (int p = 0; p < 2; p++) {
            int row = p * 32 + srow;
            *(uint4*)&ldsK[row][scol] = *(const uint4*)(Kg + ((size_t)bh * NPIX + j0 + row) * DH + scol);
            *(uint4*)&ldsV[row][scol] = *(const uint4*)(Vg + ((size_t)bh * DH + row) * NPIX + j0 + scol);
        }
        __syncthreads();

        // sim = Q K^T  (pre-scaled by dh^-0.5 * log2 e)
        f32x4 s[2][4];
#pragma unroll
        for (int ji = 0; ji < 4; ji++) {
            bf16x8 bk0 = ld_bf8(&ldsK[ji * 16 + (lane & 15)][(lane >> 4) * 8]);
            bf16x8 bk1 = ld_bf8(&ldsK[ji * 16 + (lane & 15)][32 + (lane >> 4) * 8]);
#pragma unroll
            for (int mi = 0; mi < 2; mi++) {
                f32x4 t = {0.f, 0.f, 0.f, 0.f};
                t = __builtin_amdgcn_mfma_f32_16x16x32_bf16(aq[mi][0], bk0, t, 0, 0, 0);
                t = __builtin_amdgcn_mfma_f32_16x16x32_bf16(aq[mi][1], bk1, t, 0, 0, 0);
                s[mi][ji] = t;
            }
        }

        // online softmax (rows spread over 16 lanes: shfl_xor 1/2/4/8)
#pragma unroll
        for (int mi = 0; mi < 2; mi++) {
            float nm[4], corr[4], rs[4];
#pragma unroll
            for (int r = 0; r < 4; r++) {
                float tm = fmaxf(fmaxf(s[mi][0][r], s[mi][1][r]), fmaxf(s[mi][2][r], s[mi][3][r]));
#pragma unroll
                for (int off = 1; off <= 8; off <<= 1) tm = fmaxf(tm, __shfl_xor(tm, off));
                nm[r]   = fmaxf(m_run[mi][r], tm);
                corr[r] = exp2f(m_run[mi][r] - nm[r]);
                m_run[mi][r] = nm[r];
                rs[r] = 0.f;
            }
#pragma unroll
            for (int ji = 0; ji < 4; ji++)
#pragma unroll
                for (int r = 0; r < 4; r++) {
                    float p = exp2f(s[mi][ji][r] - nm[r]);
                    s[mi][ji][r] = p;
                    rs[r] += p;
                }
#pragma unroll
            for (int r = 0; r < 4; r++) {
#pragma unroll
                for (int off = 1; off <= 8; off <<= 1) rs[r] += __shfl_xor(rs[r], off);
                l_run[mi][r] = l_run[mi][r] * corr[r] + rs[r];
            }
#pragma unroll
            for (int di = 0; di < 4; di++)
#pragma unroll
                for (int r = 0; r < 4; r++) acc[mi][di][r] *= corr[r];
            // P -> LDS (per-wave buffer) for MFMA-A relayout
#pragma unroll
            for (int ji = 0; ji < 4; ji++)
#pragma unroll
                for (int r = 0; r < 4; r++)
                    ldsP[wave][mi * 16 + (lane >> 4) * 4 + r][ji * 16 + (lane & 15)] = f2bf(s[mi][ji][r]);
        }

        // PV: acc += P * V^T
#pragma unroll
        for (int ks = 0; ks < 2; ks++) {
            bf16x8 ap0 = ld_bf8(&ldsP[wave][(lane & 15)][ks * 32 + (lane >> 4) * 8]);
            bf16x8 ap1 = ld_bf8(&ldsP[wave][16 + (lane & 15)][ks * 32 + (lane >> 4) * 8]);
#pragma unroll
            for (int di = 0; di < 4; di++) {
                bf16x8 bv = ld_bf8(&ldsV[di * 16 + (lane & 15)][ks * 32 + (lane >> 4) * 8]);
                acc[0][di] = __builtin_amdgcn_mfma_f32_16x16x32_bf16(ap0, bv, acc[0][di], 0, 0, 0);
                acc[1][di] = __builtin_amdgcn_mfma_f32_16x16x32_bf16(ap1, bv, acc[1][di], 0, 0, 0);
            }
        }
    }

    // epilogue: normalize, write [b][n][h*64+d] bf16
    const int b = bh >> 3, h = bh & 7;
#pragma unroll
    for (int mi = 0; mi < 2; mi++) {
        float inv[4];
#pragma unroll
        for (int r = 0; r < 4; r++) inv[r] = 1.0f / l_run[mi][r];
#pragma unroll
        for (int di = 0; di < 4; di++)
#pragma unroll
            for (int r = 0; r < 4; r++) {
                int q = q0 + wave * 32 + mi * 16 + (lane >> 4) * 4 + r;
                int d = di * 16 + (lane & 15);
                AT[((size_t)b * NPIX + q) * CH + h * 64 + d] = f2bf(acc[mi][di][r] * inv[r]);
            }
    }
}

// ---------------- output projection (fp32 out + bias) ---------------------
__global__ __launch_bounds__(256) void proj_out_kernel(
        const unsigned short* __restrict__ AT, const unsigned short* __restrict__ Wo,
        const float* __restrict__ bo, float* __restrict__ out) {
    const int b = blockIdx.z;
    const int o0 = blockIdx.x * 128, n0 = blockIdx.y * 128;
    f32x4 acc[4][4];
#pragma unroll
    for (int i = 0; i < 4; i++)
#pragma unroll
        for (int j = 0; j < 4; j++)
#pragma unroll
            for (int r = 0; r < 4; r++) acc[i][j][r] = 0.f;

    gemm128(Wo + (size_t)o0 * CH, AT + ((size_t)b * NPIX + n0) * CH, acc);

    const int lane = threadIdx.x & 63;
    const int wm = (threadIdx.x >> 6) & 1, wn = threadIdx.x >> 7;
#pragma unroll
    for (int i = 0; i < 4; i++) {
        const int ob = o0 + wm * 64 + i * 16 + (lane >> 4) * 4;
        float b4[4];
#pragma unroll
        for (int r = 0; r < 4; r++) b4[r] = bo[ob + r];
#pragma unroll
        for (int j = 0; j < 4; j++) {
            const int n = n0 + wn * 64 + j * 16 + (lane & 15);
#pragma unroll
            for (int r = 0; r < 4; r++)
                out[((size_t)b * CH + ob + r) * NPIX + n] = acc[i][j][r] + b4[r];
        }
    }
}

extern "C" void kernel_launch(void* const* d_in, const int* in_sizes, int n_in,
                              void* d_out, int out_size, void* d_ws, size_t ws_size,
                              hipStream_t stream) {
    const float* x   = (const float*)d_in[0];
    const float* ctx = (const float*)d_in[1];
    const float* Wq  = (const float*)d_in[2];
    const float* bq  = (const float*)d_in[3];
    const float* Wk  = (const float*)d_in[4];
    const float* bk  = (const float*)d_in[5];
    const float* Wv  = (const float*)d_in[6];
    const float* bv  = (const float*)d_in[7];
    const float* Wo  = (const float*)d_in[8];
    const float* bo  = (const float*)d_in[9];
    float* out = (float*)d_out;

    char* ws = (char*)d_ws;
    unsigned short* XT  = (unsigned short*)(ws);                 //  8 MB [b][n][c] bf16
    unsigned short* CT  = (unsigned short*)(ws + 8388608);       //  8 MB
    unsigned short* Wbf = (unsigned short*)(ws + 16777216);      //  2 MB Wq|Wk|Wv|Wo
    unsigned short* Q   = (unsigned short*)(ws + 18874368);      //  8 MB [b][h][n][d]
    unsigned short* K   = (unsigned short*)(ws + 27262976);      //  8 MB [b][h][n][d]
    unsigned short* V   = (unsigned short*)(ws + 35651584);      //  8 MB [b][h][d][n]
    unsigned short* AT  = XT;   // XT dead after proj_qkv; alias for attention output

    wconv_kernel<<<4096, 256, 0, stream>>>(Wq, Wk, Wv, Wo, Wbf);
    tconv_kernel<<<dim3(16, 32, 16), dim3(32, 8), 0, stream>>>(x, ctx, XT, CT);
    proj_qkv_kernel<<<dim3(4, 8, 24), 256, 0, stream>>>(XT, CT, Wbf, bq, bk, bv, Q, K, V);
    attn_kernel<<<dim3(8, 64), 256, 0, stream>>>(Q, K, V, AT);
    proj_out_kernel<<<dim3(4, 8, 8), 256, 0, stream>>>(AT, Wbf + 3 * 262144, bo, out);
}

// Round 2
// 124.766 us; speedup vs baseline: 1.1542x; 1.1542x over previous
//
#include <hip/hip_runtime.h>
#include <stdint.h>

#define NB   8
#define CH   512
#define NPIX 1024
#define DH   64

typedef float  f32x4  __attribute__((ext_vector_type(4)));
typedef float  f32x16 __attribute__((ext_vector_type(16)));
typedef __bf16 bf16x8 __attribute__((ext_vector_type(8)));
typedef unsigned int u32x4 __attribute__((ext_vector_type(4)));

static __device__ __forceinline__ unsigned short f2bf(float f) {
    unsigned int u = __builtin_bit_cast(unsigned int, f);
    u += 0x7FFFu + ((u >> 16) & 1u);   // RNE
    return (unsigned short)(u >> 16);
}

static __device__ __forceinline__ bf16x8 ld_bf8(const unsigned short* p) {
    return *reinterpret_cast<const bf16x8*>(p);
}

static __device__ __forceinline__ unsigned int cvtpk_bf16(float lo, float hi) {
    unsigned int r;
    asm("v_cvt_pk_bf16_f32 %0,%1,%2" : "=v"(r) : "v"(lo), "v"(hi));
    return r;
}

// ---------------- weights fp32 -> bf16, packed Wq|Wk|Wv|Wo ----------------
__global__ __launch_bounds__(256) void wconv_kernel(
        const float* __restrict__ Wq, const float* __restrict__ Wk,
        const float* __restrict__ Wv, const float* __restrict__ Wo,
        unsigned short* __restrict__ out) {
    int idx = blockIdx.x * 256 + threadIdx.x;          // 0 .. 4*512*512-1
    int which = idx >> 18;
    int off   = idx & 0x3FFFF;
    const float* src = which == 0 ? Wq : which == 1 ? Wk : which == 2 ? Wv : Wo;
    out[idx] = f2bf(src[off]);
}

// ------------- [b][c][n] fp32 -> [b][n][c] bf16 (x and context) -----------
__global__ __launch_bounds__(256) void tconv_kernel(
        const float* __restrict__ x, const float* __restrict__ ctx,
        unsigned short* __restrict__ XT, unsigned short* __restrict__ CT) {
    __shared__ float tile[32][33];
    const int z = blockIdx.z;                 // 0..15 : tensor(2) x batch(8)
    const float* src = (z < 8) ? x : ctx;
    unsigned short* dst = (z < 8) ? XT : CT;
    const int b  = z & 7;
    const int c0 = blockIdx.x * 32, n0 = blockIdx.y * 32;
    const int tx = threadIdx.x, ty = threadIdx.y;
    const float* s = src + (size_t)b * CH * NPIX;
#pragma unroll
    for (int i = 0; i < 4; i++) {
        int r = i * 8 + ty;
        tile[r][tx] = s[(size_t)(c0 + r) * NPIX + n0 + tx];
    }
    __syncthreads();
    unsigned short* d = dst + (size_t)b * NPIX * CH;
#pragma unroll
    for (int i = 0; i < 4; i++) {
        int r = i * 8 + ty;
        d[(size_t)(n0 + r) * CH + c0 + tx] = f2bf(tile[tx][r]);
    }
}

// ---------------- shared 128x128xK512 GEMM core (BK=32) -------------------
// Out[o][n] = sum_c W[o][c] * X[n][c]   (A = W rows, B^T = X rows)
static __device__ __forceinline__ void gemm128(
        const unsigned short* __restrict__ Wp,   // + o0*CH already
        const unsigned short* __restrict__ Xp,   // + (b,n0)*CH already
        f32x4 acc[4][4]) {
    __shared__ __align__(16) unsigned short lA[128][32];
    __shared__ __align__(16) unsigned short lB[128][32];
    const int tid  = threadIdx.x;
    const int lane = tid & 63;
    const int wm   = (tid >> 6) & 1, wn = tid >> 7;
    const int rr   = tid >> 2;            // 0..63
    const int cc   = (tid & 3) * 8;       // 0,8,16,24
#pragma unroll 1
    for (int kt = 0; kt < 16; kt++) {
        const int k0 = kt * 32;
        __syncthreads();
        *(uint4*)&lA[rr][cc]      = *(const uint4*)(Wp + (size_t)rr * CH + k0 + cc);
        *(uint4*)&lA[64 + rr][cc] = *(const uint4*)(Wp + (size_t)(64 + rr) * CH + k0 + cc);
        *(uint4*)&lB[rr][cc]      = *(const uint4*)(Xp + (size_t)rr * CH + k0 + cc);
        *(uint4*)&lB[64 + rr][cc] = *(const uint4*)(Xp + (size_t)(64 + rr) * CH + k0 + cc);
        __syncthreads();
        bf16x8 af[4], bfrag[4];
#pragma unroll
        for (int i = 0; i < 4; i++)
            af[i] = ld_bf8(&lA[wm * 64 + i * 16 + (lane & 15)][(lane >> 4) * 8]);
#pragma unroll
        for (int j = 0; j < 4; j++)
            bfrag[j] = ld_bf8(&lB[wn * 64 + j * 16 + (lane & 15)][(lane >> 4) * 8]);
#pragma unroll
        for (int i = 0; i < 4; i++)
#pragma unroll
            for (int j = 0; j < 4; j++)
                acc[i][j] = __builtin_amdgcn_mfma_f32_16x16x32_bf16(af[i], bfrag[j], acc[i][j], 0, 0, 0);
    }
}

// ---------------- fused Q/K/V projection --------------------------------
__global__ __launch_bounds__(256) void proj_qkv_kernel(
        const unsigned short* __restrict__ XT, const unsigned short* __restrict__ CT,
        const unsigned short* __restrict__ Wbf,
        const float* __restrict__ bq, const float* __restrict__ bk, const float* __restrict__ bv,
        unsigned short* __restrict__ Q, unsigned short* __restrict__ K, unsigned short* __restrict__ V) {
    const int z = blockIdx.z;
    const int b = z / 3, mode = z - 3 * b;       // 0=Q 1=K 2=V
    const int o0 = blockIdx.x * 128, n0 = blockIdx.y * 128;
    const unsigned short* W = Wbf + (size_t)mode * CH * CH;
    const unsigned short* X = (mode == 0 ? XT : CT) + (size_t)b * NPIX * CH;
    const float* bias = mode == 0 ? bq : mode == 1 ? bk : bv;

    f32x4 acc[4][4];
#pragma unroll
    for (int i = 0; i < 4; i++)
#pragma unroll
        for (int j = 0; j < 4; j++)
#pragma unroll
            for (int r = 0; r < 4; r++) acc[i][j][r] = 0.f;

    gemm128(W + (size_t)o0 * CH, X + (size_t)n0 * CH, acc);

    const int lane = threadIdx.x & 63;
    const int wm = (threadIdx.x >> 6) & 1, wn = threadIdx.x >> 7;
    const float qs = 0.125f * 1.44269504088896340736f;   // dim_head^-0.5 * log2(e)
#pragma unroll
    for (int i = 0; i < 4; i++) {
        const int ob = o0 + wm * 64 + i * 16 + (lane >> 4) * 4;
        const int h = ob >> 6, dd = ob & 63;
        float b4[4];
#pragma unroll
        for (int r = 0; r < 4; r++) b4[r] = bias[ob + r];
#pragma unroll
        for (int j = 0; j < 4; j++) {
            const int n = n0 + wn * 64 + j * 16 + (lane & 15);
            float v[4];
#pragma unroll
            for (int r = 0; r < 4; r++) v[r] = acc[i][j][r] + b4[r];
            if (mode == 0) {
#pragma unroll
                for (int r = 0; r < 4; r++) v[r] *= qs;
            }
            if (mode <= 1) {
                unsigned int lo = (unsigned)f2bf(v[0]) | ((unsigned)f2bf(v[1]) << 16);
                unsigned int hi = (unsigned)f2bf(v[2]) | ((unsigned)f2bf(v[3]) << 16);
                unsigned short* dst = (mode == 0 ? Q : K) +
                    (((size_t)(b * 8 + h) * NPIX) + n) * DH + dd;
                *(uint2*)dst = make_uint2(lo, hi);
            } else {
#pragma unroll
                for (int r = 0; r < 4; r++)
                    V[(((size_t)(b * 8 + h) * DH) + dd + r) * NPIX + n] = f2bf(v[r]);
            }
        }
    }
}

// ---------------- flash attention v2: swapped QK^T, in-register softmax ---
// Per wave: 32 q rows, half the keys (2-way key split). 32x32x16 MFMA.
// S^T = mfma(K, Q): lane holds col q = lane&31, rows key = (r&3)+8*(r>>2)+4*hi.
// PV: A = P (row q = lane&31, k = key), B = V[d][n] (col d = lane&31).
__global__ __launch_bounds__(256, 4) void attn_kernel(
        const unsigned short* __restrict__ Qg, const unsigned short* __restrict__ Kg,
        const unsigned short* __restrict__ Vg, unsigned short* __restrict__ AT) {
    __shared__ float ml[4][2][32];
    __shared__ float oxch[2][16][2][2][32];   // [qt][r][hi][dt][lq]

    const int bh = blockIdx.y;
    const int tid = threadIdx.x, wave = tid >> 6, lane = tid & 63;
    const int qt = wave >> 1, kh = wave & 1;
    const int q0 = blockIdx.x * 64 + qt * 32;
    const int lq = lane & 31, hi = lane >> 5;

    // Q B-fragments (held whole kernel), pre-scaled by dh^-0.5*log2e in proj
    const unsigned short* Qb = Qg + ((size_t)bh * NPIX + q0 + lq) * DH + hi * 8;
    bf16x8 qf[4];
#pragma unroll
    for (int ds = 0; ds < 4; ds++) qf[ds] = ld_bf8(Qb + ds * 16);

    f32x16 o0, o1;
#pragma unroll
    for (int r = 0; r < 16; r++) { o0[r] = 0.f; o1[r] = 0.f; }
    float m_run = -3.0e38f, l_run = 0.f;

    const unsigned short* Kbase = Kg + ((size_t)bh * NPIX + kh * 512 + lq) * DH + hi * 8;
    const unsigned short* Vbase = Vg + (size_t)bh * DH * NPIX + kh * 512 + hi * 8;

#pragma unroll 1
    for (int t = 0; t < 16; ++t) {
        // ---- K fragments (A operand): K[key0+lq][ds*16 + hi*8 ..+7]
        const unsigned short* Kp = Kbase + (size_t)t * 32 * DH;
        bf16x8 kf0 = ld_bf8(Kp), kf1 = ld_bf8(Kp + 16),
               kf2 = ld_bf8(Kp + 32), kf3 = ld_bf8(Kp + 48);
        // ---- V fragments (B operand): V[dt*32+lq][key0 + ks*16 + hi*8]
        const unsigned short* Vp = Vbase + t * 32;
        bf16x8 v00 = ld_bf8(Vp + (size_t)lq * NPIX);
        bf16x8 v01 = ld_bf8(Vp + (size_t)lq * NPIX + 16);
        bf16x8 v10 = ld_bf8(Vp + (size_t)(32 + lq) * NPIX);
        bf16x8 v11 = ld_bf8(Vp + (size_t)(32 + lq) * NPIX + 16);

        // ---- S^T = K * Q^T
        f32x16 s;
#pragma unroll
        for (int r = 0; r < 16; r++) s[r] = 0.f;
        __builtin_amdgcn_s_setprio(1);
        s = __builtin_amdgcn_mfma_f32_32x32x16_bf16(kf0, qf[0], s, 0, 0, 0);
        s = __builtin_amdgcn_mfma_f32_32x32x16_bf16(kf1, qf[1], s, 0, 0, 0);
        s = __builtin_amdgcn_mfma_f32_32x32x16_bf16(kf2, qf[2], s, 0, 0, 0);
        s = __builtin_amdgcn_mfma_f32_32x32x16_bf16(kf3, qf[3], s, 0, 0, 0);
        __builtin_amdgcn_s_setprio(0);

        // ---- tile max (tree) + cross-half
        float t8[8], t4[4];
#pragma unroll
        for (int i = 0; i < 8; i++) t8[i] = fmaxf(s[2 * i], s[2 * i + 1]);
#pragma unroll
        for (int i = 0; i < 4; i++) t4[i] = fmaxf(t8[2 * i], t8[2 * i + 1]);
        float pm = fmaxf(fmaxf(t4[0], t4[1]), fmaxf(t4[2], t4[3]));
        pm = fmaxf(pm, __shfl_xor(pm, 32));

        // ---- defer-max: rescale only when max grew past THR=8 (log2 domain)
        if (__any(pm > m_run + 8.0f)) {
            float mn   = fmaxf(m_run, pm);
            float corr = exp2f(m_run - mn);
            l_run *= corr;
            m_run = mn;
#pragma unroll
            for (int r = 0; r < 16; r++) {
                float cr = __shfl(corr, (r & 3) + 8 * (r >> 2) + 4 * hi);
                o0[r] *= cr; o1[r] *= cr;
            }
        }

        // ---- P = exp2(S - m), row-sum
        float p[16];
#pragma unroll
        for (int r = 0; r < 16; r++) p[r] = exp2f(s[r] - m_run);
        float s8[8], s4[4];
#pragma unroll
        for (int i = 0; i < 8; i++) s8[i] = p[2 * i] + p[2 * i + 1];
#pragma unroll
        for (int i = 0; i < 4; i++) s4[i] = s8[2 * i] + s8[2 * i + 1];
        float rs = (s4[0] + s4[1]) + (s4[2] + s4[3]);
        rs += __shfl_xor(rs, 32);
        l_run += rs;

        // ---- pack P -> bf16 A-fragments (keys hi*8..+7 per half, +16*ks)
        bf16x8 pa[2];
#pragma unroll
        for (int ks = 0; ks < 2; ks++) {
            const int bse = ks * 8;
            unsigned int X0 = cvtpk_bf16(p[bse + 0], p[bse + 1]);
            unsigned int X1 = cvtpk_bf16(p[bse + 2], p[bse + 3]);
            unsigned int X2 = cvtpk_bf16(p[bse + 4], p[bse + 5]);
            unsigned int X3 = cvtpk_bf16(p[bse + 6], p[bse + 7]);
            unsigned int pX0 = __shfl_xor(X0, 32);
            unsigned int pX1 = __shfl_xor(X1, 32);
            unsigned int pX2 = __shfl_xor(X2, 32);
            unsigned int pX3 = __shfl_xor(X3, 32);
            u32x4 w;
            w[0] = hi ? pX2 : X0;    // keys base+0,1   (hi=1: base+8,9)
            w[1] = hi ? pX3 : X1;    // keys base+2,3   (hi=1: base+10,11)
            w[2] = hi ? X2 : pX0;    // keys base+4,5   (hi=1: base+12,13)
            w[3] = hi ? X3 : pX1;    // keys base+6,7   (hi=1: base+14,15)
            pa[ks] = __builtin_bit_cast(bf16x8, w);
        }

        // ---- O += P * V
        __builtin_amdgcn_s_setprio(1);
        o0 = __builtin_amdgcn_mfma_f32_32x32x16_bf16(pa[0], v00, o0, 0, 0, 0);
        o0 = __builtin_amdgcn_mfma_f32_32x32x16_bf16(pa[1], v01, o0, 0, 0, 0);
        o1 = __builtin_amdgcn_mfma_f32_32x32x16_bf16(pa[0], v10, o1, 0, 0, 0);
        o1 = __builtin_amdgcn_mfma_f32_32x32x16_bf16(pa[1], v11, o1, 0, 0, 0);
        __builtin_amdgcn_s_setprio(0);
    }

    // ---- merge the two key-halves (wave pairs), normalize, write out
    if (lane < 32) { ml[wave][0][lq] = m_run; ml[wave][1][lq] = l_run; }
    __syncthreads();
    float m2 = ml[wave ^ 1][0][lq], l2 = ml[wave ^ 1][1][lq];
    float mM   = fmaxf(m_run, m2);
    float sown = exp2f(m_run - mM);
    float lT   = l_run * sown + l2 * exp2f(m2 - mM);
    float inv  = sown / lT;
#pragma unroll
    for (int r = 0; r < 16; r++) {
        float fac = __shfl(inv, (r & 3) + 8 * (r >> 2) + 4 * hi);
        o0[r] *= fac; o1[r] *= fac;
    }
    if (kh == 1) {
#pragma unroll
        for (int r = 0; r < 16; r++) {
            oxch[qt][r][hi][0][lq] = o0[r];
            oxch[qt][r][hi][1][lq] = o1[r];
        }
    }
    __syncthreads();
    if (kh == 0) {
        const int b = bh >> 3, h = bh & 7;
#pragma unroll
        for (int r = 0; r < 16; r++) {
            int q = q0 + (r & 3) + 8 * (r >> 2) + 4 * hi;
            float f0 = o0[r] + oxch[qt][r][hi][0][lq];
            float f1 = o1[r] + oxch[qt][r][hi][1][lq];
            unsigned short* dst = AT + ((size_t)b * NPIX + q) * CH + h * 64 + lq;
            dst[0]  = f2bf(f0);
            dst[32] = f2bf(f1);
        }
    }
}

// ---------------- output projection (fp32 out + bias) ---------------------
__global__ __launch_bounds__(256) void proj_out_kernel(
        const unsigned short* __restrict__ AT, const unsigned short* __restrict__ Wo,
        const float* __restrict__ bo, float* __restrict__ out) {
    const int b = blockIdx.z;
    const int o0 = blockIdx.x * 128, n0 = blockIdx.y * 128;
    f32x4 acc[4][4];
#pragma unroll
    for (int i = 0; i < 4; i++)
#pragma unroll
        for (int j = 0; j < 4; j++)
#pragma unroll
            for (int r = 0; r < 4; r++) acc[i][j][r] = 0.f;

    gemm128(Wo + (size_t)o0 * CH, AT + ((size_t)b * NPIX + n0) * CH, acc);

    const int lane = threadIdx.x & 63;
    const int wm = (threadIdx.x >> 6) & 1, wn = threadIdx.x >> 7;
#pragma unroll
    for (int i = 0; i < 4; i++) {
        const int ob = o0 + wm * 64 + i * 16 + (lane >> 4) * 4;
        float b4[4];
#pragma unroll
        for (int r = 0; r < 4; r++) b4[r] = bo[ob + r];
#pragma unroll
        for (int j = 0; j < 4; j++) {
            const int n = n0 + wn * 64 + j * 16 + (lane & 15);
#pragma unroll
            for (int r = 0; r < 4; r++)
                out[((size_t)b * CH + ob + r) * NPIX + n] = acc[i][j][r] + b4[r];
        }
    }
}

extern "C" void kernel_launch(void* const* d_in, const int* in_sizes, int n_in,
                              void* d_out, int out_size, void* d_ws, size_t ws_size,
                              hipStream_t stream) {
    const float* x   = (const float*)d_in[0];
    const float* ctx = (const float*)d_in[1];
    const float* Wq  = (const float*)d_in[2];
    const float* bq  = (const float*)d_in[3];
    const float* Wk  = (const float*)d_in[4];
    const float* bk  = (const float*)d_in[5];
    const float* Wv  = (const float*)d_in[6];
    const float* bv  = (const float*)d_in[7];
    const float* Wo  = (const float*)d_in[8];
    const float* bo  = (const float*)d_in[9];
    float* out = (float*)d_out;

    char* ws = (char*)d_ws;
    unsigned short* XT  = (unsigned short*)(ws);                 //  8 MB [b][n][c] bf16
    unsigned short* CT  = (unsigned short*)(ws + 8388608);       //  8 MB
    unsigned short* Wbf = (unsigned short*)(ws + 16777216);      //  2 MB Wq|Wk|Wv|Wo
    unsigned short* Q   = (unsigned short*)(ws + 18874368);      //  8 MB [b][h][n][d]
    unsigned short* K   = (unsigned short*)(ws + 27262976);      //  8 MB [b][h][n][d]
    unsigned short* V   = (unsigned short*)(ws + 35651584);      //  8 MB [b][h][d][n]
    unsigned short* AT  = XT;   // XT dead after proj_qkv; alias for attention output

    wconv_kernel<<<4096, 256, 0, stream>>>(Wq, Wk, Wv, Wo, Wbf);
    tconv_kernel<<<dim3(16, 32, 16), dim3(32, 8), 0, stream>>>(x, ctx, XT, CT);
    proj_qkv_kernel<<<dim3(4, 8, 24), 256, 0, stream>>>(XT, CT, Wbf, bq, bk, bv, Q, K, V);
    attn_kernel<<<dim3(16, 64), 256, 0, stream>>>(Q, K, V, AT);
    proj_out_kernel<<<dim3(4, 8, 8), 256, 0, stream>>>(AT, Wbf + 3 * 262144, bo, out);
}